// Round 18
// baseline (93.838 us; speedup 1.0000x reference)
//
#include <hip/hip_runtime.h>

// MultiGaussSpatialConv: B=1, N=M=8192, D=3, C=16, fp32.
// out[n,c] = sum_i w_i * (sum_m e_i(n,m) yf[m,c]) / (sum_m e_i(n,m))
// e_i = exp(-d2/(2 s^2)), 1/(2 s^2) = {200, 50, 12.5} -> e0 = e2^16, e1 = e2^4.
//
// R18 (= R17, NCH 8->4): final addressable slack -- halve partial traffic.
// R17 structure: arg dot-products on the MFMA pipe via split-fp16 rank-13
// product; v_exp_f32; per-wave LDS transpose (no barriers); fp16 power
// chain; e-MFMA with yf as A operand. Verified absmax 1.953e-3.

static constexpr int Nn = 8192;
static constexpr int Mm = 8192;
static constexpr int NCH = 4;               // m-chunks (halved partials)
static constexpr int MC  = Mm / NCH;        // 2048 m per chunk
static constexpr int NKT = MC / 32;         // kt per wave (64)
static constexpr float KC = 36.0673761f;    // 25 * log2(e)
static constexpr float KD = -18.0336880f;   // -12.5 * log2(e)

typedef _Float16 half8 __attribute__((ext_vector_type(8)));
typedef __fp16  fp16x2 __attribute__((ext_vector_type(2)));
typedef float  float2v __attribute__((ext_vector_type(2)));
typedef float  float4v __attribute__((ext_vector_type(4)));

#define MFMA_F16 __builtin_amdgcn_mfma_f32_16x16x32_f16
#define EXP2F(v) __builtin_amdgcn_exp2f(v)

// ---------------- prep: y -> split-fp16 arg-A-frags; yf -> fp16 frags
__global__ __launch_bounds__(256) void mgsc_prep(
    const float* __restrict__ y, const float* __restrict__ yf,
    _Float16* __restrict__ fragy, _Float16* __restrict__ fragf)
{
    const int t = blockIdx.x * 256 + threadIdx.x;   // 0 .. Mm*32-1
    const int m = t >> 5, kk = t & 31;
    const float ax = y[3 * m], ay = y[3 * m + 1], az = y[3 * m + 2];
    const float Ycx = KC * ax, Ycy = KC * ay, Ycz = KC * az;
    const _Float16 Yhx = (_Float16)Ycx, Yhy = (_Float16)Ycy, Yhz = (_Float16)Ycz;
    const _Float16 Ylx = (_Float16)(Ycx - (float)Yhx);
    const _Float16 Yly = (_Float16)(Ycy - (float)Yhy);
    const _Float16 Ylz = (_Float16)(Ycz - (float)Yhz);
    const float Wy = KD * __fmaf_rn(ax, ax, __fmaf_rn(ay, ay, az * az));
    const _Float16 Wyh = (_Float16)Wy;
    const _Float16 Wyl = (_Float16)(Wy - (float)Wyh);
    _Float16 v = (_Float16)0.0f;
    switch (kk) {
        case 0: case 6: v = Yhx; break;
        case 1: case 7: v = Yhy; break;
        case 2: case 8: v = Yhz; break;
        case 3: v = Ylx; break;
        case 4: v = Yly; break;
        case 5: v = Ylz; break;
        case 9:  v = Wyh; break;
        case 10: v = Wyl; break;
        case 11: case 12: v = (_Float16)1.0f; break;
        default: break;
    }
    // A-frag layout: idx = (m>>4)*512 + ((kk>>3)*16 + (m&15))*8 + (kk&7)
    const int idx = ((m >> 4) << 9) + ((((kk >> 3) << 4) + (m & 15)) << 3) + (kk & 7);
    fragy[idx] = v;
    if (t < Mm * 16) {                              // yf frags (same as R13)
        const int m2 = t >> 4, c2 = t & 15;
        const int idx2 = ((m2 >> 5) << 9) + ((((m2 & 31) >> 3) << 4) + c2) * 8 + (m2 & 7);
        fragf[idx2] = (_Float16)yf[t];              // RNE
    }
}

// ---------------- main: grid (128, NCH); 4 waves/block, one n-tile per wave
__global__ __launch_bounds__(256, 4) void mgsc_main(
    const float* __restrict__ x, const _Float16* __restrict__ fragy,
    const _Float16* __restrict__ fragf, float* __restrict__ part)
{
    __shared__ float eT[4][16 * 34];                // per-WAVE transpose scratch

    const int tid  = threadIdx.x;
    const int wave = tid >> 6, lane = tid & 63;
    const int g    = lane >> 4, c = lane & 15;      // c = n_local
    const int xb   = blockIdx.x, yb = blockIdx.y;
    const int n0   = (xb * 4 + wave) * 16;
    const int nrow = n0 + c;

    // ---- build x-side B operand for the arg-MFMA (hoisted, per lane)
    const float xx = x[3 * nrow], xy = x[3 * nrow + 1], xz = x[3 * nrow + 2];
    const _Float16 xhx = (_Float16)xx, xhy = (_Float16)xy, xhz = (_Float16)xz;
    const _Float16 xlx = (_Float16)(xx - (float)xhx);
    const _Float16 xly = (_Float16)(xy - (float)xhy);
    const _Float16 xlz = (_Float16)(xz - (float)xhz);
    const float Wx = KD * __fmaf_rn(xx, xx, __fmaf_rn(xy, xy, xz * xz));
    const _Float16 Wxh = (_Float16)Wx;
    const _Float16 Wxl = (_Float16)(Wx - (float)Wxh);
    const _Float16 z16 = (_Float16)0.0f, one16 = (_Float16)1.0f;
    half8 B1;
    if (g == 0)      B1 = half8{xhx, xhy, xhz, xhx, xhy, xhz, xlx, xly};
    else if (g == 1) B1 = half8{xlz, one16, one16, Wxh, Wxl, z16, z16, z16};
    else             B1 = half8{z16, z16, z16, z16, z16, z16, z16, z16};

    float4v acc0 = {0.f, 0.f, 0.f, 0.f}, acc1 = acc0, acc2 = acc0;
    float4v dac0 = acc0, dac1 = acc0, dac2 = acc0;
    const float4v z4 = acc0;

    const _Float16 bv = (c == 0) ? one16 : z16;     // A-ones row 0 -> dens
    half8 boneA = {bv, bv, bv, bv, bv, bv, bv, bv};

    float* eTw = &eT[wave][0];
    const size_t ybase = (size_t)(yb * (MC / 16)) << 9;  // 16-m blocks per chunk
    const size_t fbase = (size_t)(yb * NKT) << 9;

    for (int ktl = 0; ktl < NKT; ++ktl) {
        const half8 A1a = *reinterpret_cast<const half8*>(fragy + ybase + ((size_t)(2 * ktl) << 9) + (lane << 3));
        const half8 A1b = *reinterpret_cast<const half8*>(fragy + ybase + ((size_t)(2 * ktl + 1) << 9) + (lane << 3));
        const half8 Af  = *reinterpret_cast<const half8*>(fragf + fbase + ((size_t)ktl << 9) + (lane << 3));

        // arg^T: col = n (lane&15), rows m = 4g+r (D1), 16+4g+r (D2)
        const float4v D1 = MFMA_F16(A1a, B1, z4, 0, 0, 0);
        const float4v D2 = MFMA_F16(A1b, B1, z4, 0, 0, 0);

        // exp + intra-wave transpose (n-major, stride 34, b64 ops)
        float* wp = eTw + c * 34;
        *reinterpret_cast<float2v*>(wp + 4 * g)          = float2v{EXP2F(D1[0]), EXP2F(D1[1])};
        *reinterpret_cast<float2v*>(wp + 4 * g + 2)      = float2v{EXP2F(D1[2]), EXP2F(D1[3])};
        *reinterpret_cast<float2v*>(wp + 16 + 4 * g)     = float2v{EXP2F(D2[0]), EXP2F(D2[1])};
        *reinterpret_cast<float2v*>(wp + 16 + 4 * g + 2) = float2v{EXP2F(D2[2]), EXP2F(D2[3])};
        const float* rp = eTw + c * 34 + 8 * g;         // k = m = 8g + j
        const float2v r0 = *reinterpret_cast<const float2v*>(rp);
        const float2v r1 = *reinterpret_cast<const float2v*>(rp + 2);
        const float2v r2 = *reinterpret_cast<const float2v*>(rp + 4);
        const float2v r3 = *reinterpret_cast<const float2v*>(rp + 6);

        union { fp16x2 h2[4]; half8 v; } E2p, E1p, E0p;
        const float2v rr[4] = {r0, r1, r2, r3};
#pragma unroll
        for (int jj = 0; jj < 4; ++jj) {
            E2p.h2[jj] = __builtin_amdgcn_cvt_pkrtz(rr[jj].x, rr[jj].y);
            const fp16x2 s2 = E2p.h2[jj] * E2p.h2[jj];  // v_pk_mul_f16
            E1p.h2[jj] = s2 * s2;                        // e2^4  (sigma 0.1)
            const fp16x2 s1 = E1p.h2[jj] * E1p.h2[jj];
            E0p.h2[jj] = s1 * s1;                        // e2^16 (sigma 0.05)
        }
        // e-MFMA: A = yf^T (row=c, k=m), B = e^T (k=m, col=n)
        acc0 = MFMA_F16(Af, E0p.v, acc0, 0, 0, 0);
        acc1 = MFMA_F16(Af, E1p.v, acc1, 0, 0, 0);
        acc2 = MFMA_F16(Af, E2p.v, acc2, 0, 0, 0);
        dac0 = MFMA_F16(boneA, E0p.v, dac0, 0, 0, 0);
        dac1 = MFMA_F16(boneA, E1p.v, dac1, 0, 0, 0);
        dac2 = MFMA_F16(boneA, E2p.v, dac2, 0, 0, 0);
    }

    // ---- epilogue: D col = n = c(lane), rows = channel 4g + r
    float* row = part + ((size_t)yb * Nn + (n0 + c)) * 52;
#pragma unroll
    for (int r = 0; r < 4; ++r) {
        const int ch = 4 * g + r;
        row[ch]      = acc0[r];
        row[16 + ch] = acc1[r];
        row[32 + ch] = acc2[r];
    }
    if (g == 0) {                                   // dens live in row 0
        row[48] = dac0[0];
        row[49] = dac1[0];
        row[50] = dac2[0];
    }
}

// ---------------- reduce: thread (n,c) sums NCH chunks, finalizes
__global__ __launch_bounds__(256) void mgsc_reduce(
    const float* __restrict__ part, float* __restrict__ out)
{
    const int t = blockIdx.x * 256 + threadIdx.x;   // 0 .. Nn*16-1
    const int n = t >> 4, c = t & 15;
    float s0 = 0.f, s1 = 0.f, s2 = 0.f, d0 = 0.f, d1 = 0.f, d2 = 0.f;
#pragma unroll
    for (int k = 0; k < NCH; ++k) {
        const float* row = part + ((size_t)k * Nn + n) * 52;
        s0 += row[c];
        s1 += row[16 + c];
        s2 += row[32 + c];
        d0 += row[48];
        d1 += row[49];
        d2 += row[50];
    }
    out[(size_t)n * 16 + c] = 0.3f * s0 / d0 + 0.3f * s1 / d1 + 0.4f * s2 / d2;
}

// ---------------- fused VALU fallback (workspace too small)
__global__ __launch_bounds__(256) void mgsc_fused(
    const float* __restrict__ x, const float* __restrict__ y,
    const float* __restrict__ yf, float* __restrict__ out)
{
    __shared__ float yS[256 * 3];
    __shared__ float yfS[256 * 16];
    const int tid = threadIdx.x;
    const int n   = blockIdx.x * 256 + tid;
    const float xx = x[3 * n], xy = x[3 * n + 1], xz = x[3 * n + 2];
    float a0[16], a1[16], a2[16];
#pragma unroll
    for (int c = 0; c < 16; ++c) { a0[c] = 0.f; a1[c] = 0.f; a2[c] = 0.f; }
    float den0 = 0.f, den1 = 0.f, den2 = 0.f;
    for (int mt = 0; mt < Mm; mt += 256) {
        const float4* ysrc = reinterpret_cast<const float4*>(y + (size_t)mt * 3);
        if (tid < 192) reinterpret_cast<float4*>(yS)[tid] = ysrc[tid];
        const float4* fsrc = reinterpret_cast<const float4*>(yf + (size_t)mt * 16);
#pragma unroll
        for (int k = 0; k < 4; ++k)
            reinterpret_cast<float4*>(yfS)[tid + 256 * k] = fsrc[tid + 256 * k];
        __syncthreads();
        for (int mm = 0; mm < 256; ++mm) {
            const float dx = xx - yS[3 * mm], dy = xy - yS[3 * mm + 1], dz = xz - yS[3 * mm + 2];
            const float d2 = dx * dx + dy * dy + dz * dz;
            const float e2 = __expf(-12.5f * d2);
            const float t = e2 * e2, e1 = t * t, u = e1 * e1, e0 = u * u;
            den0 += e0; den1 += e1; den2 += e2;
            const float4* fr = reinterpret_cast<const float4*>(yfS + mm * 16);
#pragma unroll
            for (int k = 0; k < 4; ++k) {
                const float4 f = fr[k];
                a0[4*k+0] += e0 * f.x; a0[4*k+1] += e0 * f.y; a0[4*k+2] += e0 * f.z; a0[4*k+3] += e0 * f.w;
                a1[4*k+0] += e1 * f.x; a1[4*k+1] += e1 * f.y; a1[4*k+2] += e1 * f.z; a1[4*k+3] += e1 * f.w;
                a2[4*k+0] += e2 * f.x; a2[4*k+1] += e2 * f.y; a2[4*k+2] += e2 * f.z; a2[4*k+3] += e2 * f.w;
            }
        }
        __syncthreads();
    }
    const float r0 = 0.3f / den0, r1 = 0.3f / den1, r2 = 0.4f / den2;
#pragma unroll
    for (int c = 0; c < 16; ++c)
        out[(size_t)n * 16 + c] = a0[c] * r0 + a1[c] * r1 + a2[c] * r2;
}

extern "C" void kernel_launch(void* const* d_in, const int* in_sizes, int n_in,
                              void* d_out, int out_size, void* d_ws, size_t ws_size,
                              hipStream_t stream) {
    const float* x  = (const float*)d_in[0];
    const float* y  = (const float*)d_in[1];
    const float* yf = (const float*)d_in[2];
    float* out = (float*)d_out;

    const size_t fragyB = (size_t)(Mm / 16) * 512 * sizeof(_Float16); // 512 KB
    const size_t fragfB = (size_t)Mm * 16 * sizeof(_Float16);         // 256 KB
    const size_t partB  = (size_t)NCH * Nn * 52 * sizeof(float);      // 6.8 MB
    if (fragyB + fragfB + partB > ws_size) {
        mgsc_fused<<<Nn / 256, 256, 0, stream>>>(x, y, yf, out);
        return;
    }
    _Float16* fragy = (_Float16*)d_ws;
    _Float16* fragf = (_Float16*)((char*)d_ws + fragyB);
    float*    part  = (float*)((char*)d_ws + fragyB + fragfB);

    mgsc_prep<<<(Mm * 32) / 256, 256, 0, stream>>>(y, yf, fragy, fragf);
    mgsc_main<<<dim3(Nn / 64, NCH), 256, 0, stream>>>(x, fragy, fragf, part);
    mgsc_reduce<<<(Nn * 16) / 256, 256, 0, stream>>>(part, out);
}

// Round 19
// 87.953 us; speedup vs baseline: 1.0669x; 1.0669x over previous
//
#include <hip/hip_runtime.h>

// MultiGaussSpatialConv: B=1, N=M=8192, D=3, C=16, fp32.
// out[n,c] = sum_i w_i * (sum_m e_i(n,m) yf[m,c]) / (sum_m e_i(n,m))
// e_i = exp(-d2/(2 s^2)), 1/(2 s^2) = {200, 50, 12.5} -> e0 = e2^16, e1 = e2^4.
//
// R19 = exact restore of R17 (best: 88.2 us, absmax 1.953e-3). R18's NCH=4
// regressed (grid 512 = 2 blocks/CU too few for this body). Final structure:
//  - prep: y -> split-fp16 rank-13 arg-A-frags; yf -> fp16 B-frags (global,
//    L2-resident).
//  - main: arg^T via one 16x16x32 f16 MFMA per 16 m (split-fp16, ~5e-5 err);
//    v_exp_f32; per-wave LDS transpose (no barriers); packed fp16 power
//    chain (e2 -> e2^4 -> e2^16, quantization cancels in num/den ratio);
//    e-MFMA with yf as A operand. Grid (128,8), 4 waves/block.
//  - reduce: sums 8 partials, finalizes weighted ratio.

static constexpr int Nn = 8192;
static constexpr int Mm = 8192;
static constexpr int NCH = 8;               // m-chunks
static constexpr int MC  = Mm / NCH;        // 1024 m per chunk
static constexpr int NKT = MC / 32;         // kt per wave (32)
static constexpr float KC = 36.0673761f;    // 25 * log2(e)
static constexpr float KD = -18.0336880f;   // -12.5 * log2(e)

typedef _Float16 half8 __attribute__((ext_vector_type(8)));
typedef __fp16  fp16x2 __attribute__((ext_vector_type(2)));
typedef float  float2v __attribute__((ext_vector_type(2)));
typedef float  float4v __attribute__((ext_vector_type(4)));

#define MFMA_F16 __builtin_amdgcn_mfma_f32_16x16x32_f16
#define EXP2F(v) __builtin_amdgcn_exp2f(v)

// ---------------- prep: y -> split-fp16 arg-A-frags; yf -> fp16 frags
__global__ __launch_bounds__(256) void mgsc_prep(
    const float* __restrict__ y, const float* __restrict__ yf,
    _Float16* __restrict__ fragy, _Float16* __restrict__ fragf)
{
    const int t = blockIdx.x * 256 + threadIdx.x;   // 0 .. Mm*32-1
    const int m = t >> 5, kk = t & 31;
    const float ax = y[3 * m], ay = y[3 * m + 1], az = y[3 * m + 2];
    const float Ycx = KC * ax, Ycy = KC * ay, Ycz = KC * az;
    const _Float16 Yhx = (_Float16)Ycx, Yhy = (_Float16)Ycy, Yhz = (_Float16)Ycz;
    const _Float16 Ylx = (_Float16)(Ycx - (float)Yhx);
    const _Float16 Yly = (_Float16)(Ycy - (float)Yhy);
    const _Float16 Ylz = (_Float16)(Ycz - (float)Yhz);
    const float Wy = KD * __fmaf_rn(ax, ax, __fmaf_rn(ay, ay, az * az));
    const _Float16 Wyh = (_Float16)Wy;
    const _Float16 Wyl = (_Float16)(Wy - (float)Wyh);
    _Float16 v = (_Float16)0.0f;
    switch (kk) {
        case 0: case 6: v = Yhx; break;
        case 1: case 7: v = Yhy; break;
        case 2: case 8: v = Yhz; break;
        case 3: v = Ylx; break;
        case 4: v = Yly; break;
        case 5: v = Ylz; break;
        case 9:  v = Wyh; break;
        case 10: v = Wyl; break;
        case 11: case 12: v = (_Float16)1.0f; break;
        default: break;
    }
    // A-frag layout: idx = (m>>4)*512 + ((kk>>3)*16 + (m&15))*8 + (kk&7)
    const int idx = ((m >> 4) << 9) + ((((kk >> 3) << 4) + (m & 15)) << 3) + (kk & 7);
    fragy[idx] = v;
    if (t < Mm * 16) {                              // yf frags (same as R13)
        const int m2 = t >> 4, c2 = t & 15;
        const int idx2 = ((m2 >> 5) << 9) + ((((m2 & 31) >> 3) << 4) + c2) * 8 + (m2 & 7);
        fragf[idx2] = (_Float16)yf[t];              // RNE
    }
}

// ---------------- main: grid (128, NCH); 4 waves/block, one n-tile per wave
__global__ __launch_bounds__(256, 4) void mgsc_main(
    const float* __restrict__ x, const _Float16* __restrict__ fragy,
    const _Float16* __restrict__ fragf, float* __restrict__ part)
{
    __shared__ float eT[4][16 * 34];                // per-WAVE transpose scratch

    const int tid  = threadIdx.x;
    const int wave = tid >> 6, lane = tid & 63;
    const int g    = lane >> 4, c = lane & 15;      // c = n_local
    const int xb   = blockIdx.x, yb = blockIdx.y;
    const int n0   = (xb * 4 + wave) * 16;
    const int nrow = n0 + c;

    // ---- build x-side B operand for the arg-MFMA (hoisted, per lane)
    const float xx = x[3 * nrow], xy = x[3 * nrow + 1], xz = x[3 * nrow + 2];
    const _Float16 xhx = (_Float16)xx, xhy = (_Float16)xy, xhz = (_Float16)xz;
    const _Float16 xlx = (_Float16)(xx - (float)xhx);
    const _Float16 xly = (_Float16)(xy - (float)xhy);
    const _Float16 xlz = (_Float16)(xz - (float)xhz);
    const float Wx = KD * __fmaf_rn(xx, xx, __fmaf_rn(xy, xy, xz * xz));
    const _Float16 Wxh = (_Float16)Wx;
    const _Float16 Wxl = (_Float16)(Wx - (float)Wxh);
    const _Float16 z16 = (_Float16)0.0f, one16 = (_Float16)1.0f;
    half8 B1;
    if (g == 0)      B1 = half8{xhx, xhy, xhz, xhx, xhy, xhz, xlx, xly};
    else if (g == 1) B1 = half8{xlz, one16, one16, Wxh, Wxl, z16, z16, z16};
    else             B1 = half8{z16, z16, z16, z16, z16, z16, z16, z16};

    float4v acc0 = {0.f, 0.f, 0.f, 0.f}, acc1 = acc0, acc2 = acc0;
    float4v dac0 = acc0, dac1 = acc0, dac2 = acc0;
    const float4v z4 = acc0;

    const _Float16 bv = (c == 0) ? one16 : z16;     // A-ones row 0 -> dens
    half8 boneA = {bv, bv, bv, bv, bv, bv, bv, bv};

    float* eTw = &eT[wave][0];
    const size_t ybase = (size_t)(yb * (MC / 16)) << 9;  // 16-m blocks per chunk
    const size_t fbase = (size_t)(yb * NKT) << 9;

    for (int ktl = 0; ktl < NKT; ++ktl) {
        const half8 A1a = *reinterpret_cast<const half8*>(fragy + ybase + ((size_t)(2 * ktl) << 9) + (lane << 3));
        const half8 A1b = *reinterpret_cast<const half8*>(fragy + ybase + ((size_t)(2 * ktl + 1) << 9) + (lane << 3));
        const half8 Af  = *reinterpret_cast<const half8*>(fragf + fbase + ((size_t)ktl << 9) + (lane << 3));

        // arg^T: col = n (lane&15), rows m = 4g+r (D1), 16+4g+r (D2)
        const float4v D1 = MFMA_F16(A1a, B1, z4, 0, 0, 0);
        const float4v D2 = MFMA_F16(A1b, B1, z4, 0, 0, 0);

        // exp + intra-wave transpose (n-major, stride 34, b64 ops)
        float* wp = eTw + c * 34;
        *reinterpret_cast<float2v*>(wp + 4 * g)          = float2v{EXP2F(D1[0]), EXP2F(D1[1])};
        *reinterpret_cast<float2v*>(wp + 4 * g + 2)      = float2v{EXP2F(D1[2]), EXP2F(D1[3])};
        *reinterpret_cast<float2v*>(wp + 16 + 4 * g)     = float2v{EXP2F(D2[0]), EXP2F(D2[1])};
        *reinterpret_cast<float2v*>(wp + 16 + 4 * g + 2) = float2v{EXP2F(D2[2]), EXP2F(D2[3])};
        const float* rp = eTw + c * 34 + 8 * g;         // k = m = 8g + j
        const float2v r0 = *reinterpret_cast<const float2v*>(rp);
        const float2v r1 = *reinterpret_cast<const float2v*>(rp + 2);
        const float2v r2 = *reinterpret_cast<const float2v*>(rp + 4);
        const float2v r3 = *reinterpret_cast<const float2v*>(rp + 6);

        union { fp16x2 h2[4]; half8 v; } E2p, E1p, E0p;
        const float2v rr[4] = {r0, r1, r2, r3};
#pragma unroll
        for (int jj = 0; jj < 4; ++jj) {
            E2p.h2[jj] = __builtin_amdgcn_cvt_pkrtz(rr[jj].x, rr[jj].y);
            const fp16x2 s2 = E2p.h2[jj] * E2p.h2[jj];  // v_pk_mul_f16
            E1p.h2[jj] = s2 * s2;                        // e2^4  (sigma 0.1)
            const fp16x2 s1 = E1p.h2[jj] * E1p.h2[jj];
            E0p.h2[jj] = s1 * s1;                        // e2^16 (sigma 0.05)
        }
        // e-MFMA: A = yf^T (row=c, k=m), B = e^T (k=m, col=n)
        acc0 = MFMA_F16(Af, E0p.v, acc0, 0, 0, 0);
        acc1 = MFMA_F16(Af, E1p.v, acc1, 0, 0, 0);
        acc2 = MFMA_F16(Af, E2p.v, acc2, 0, 0, 0);
        dac0 = MFMA_F16(boneA, E0p.v, dac0, 0, 0, 0);
        dac1 = MFMA_F16(boneA, E1p.v, dac1, 0, 0, 0);
        dac2 = MFMA_F16(boneA, E2p.v, dac2, 0, 0, 0);
    }

    // ---- epilogue: D col = n = c(lane), rows = channel 4g + r
    float* row = part + ((size_t)yb * Nn + (n0 + c)) * 52;
#pragma unroll
    for (int r = 0; r < 4; ++r) {
        const int ch = 4 * g + r;
        row[ch]      = acc0[r];
        row[16 + ch] = acc1[r];
        row[32 + ch] = acc2[r];
    }
    if (g == 0) {                                   // dens live in row 0
        row[48] = dac0[0];
        row[49] = dac1[0];
        row[50] = dac2[0];
    }
}

// ---------------- reduce: thread (n,c) sums NCH chunks, finalizes
__global__ __launch_bounds__(256) void mgsc_reduce(
    const float* __restrict__ part, float* __restrict__ out)
{
    const int t = blockIdx.x * 256 + threadIdx.x;   // 0 .. Nn*16-1
    const int n = t >> 4, c = t & 15;
    float s0 = 0.f, s1 = 0.f, s2 = 0.f, d0 = 0.f, d1 = 0.f, d2 = 0.f;
#pragma unroll
    for (int k = 0; k < NCH; ++k) {
        const float* row = part + ((size_t)k * Nn + n) * 52;
        s0 += row[c];
        s1 += row[16 + c];
        s2 += row[32 + c];
        d0 += row[48];
        d1 += row[49];
        d2 += row[50];
    }
    out[(size_t)n * 16 + c] = 0.3f * s0 / d0 + 0.3f * s1 / d1 + 0.4f * s2 / d2;
}

// ---------------- fused VALU fallback (workspace too small)
__global__ __launch_bounds__(256) void mgsc_fused(
    const float* __restrict__ x, const float* __restrict__ y,
    const float* __restrict__ yf, float* __restrict__ out)
{
    __shared__ float yS[256 * 3];
    __shared__ float yfS[256 * 16];
    const int tid = threadIdx.x;
    const int n   = blockIdx.x * 256 + tid;
    const float xx = x[3 * n], xy = x[3 * n + 1], xz = x[3 * n + 2];
    float a0[16], a1[16], a2[16];
#pragma unroll
    for (int c = 0; c < 16; ++c) { a0[c] = 0.f; a1[c] = 0.f; a2[c] = 0.f; }
    float den0 = 0.f, den1 = 0.f, den2 = 0.f;
    for (int mt = 0; mt < Mm; mt += 256) {
        const float4* ysrc = reinterpret_cast<const float4*>(y + (size_t)mt * 3);
        if (tid < 192) reinterpret_cast<float4*>(yS)[tid] = ysrc[tid];
        const float4* fsrc = reinterpret_cast<const float4*>(yf + (size_t)mt * 16);
#pragma unroll
        for (int k = 0; k < 4; ++k)
            reinterpret_cast<float4*>(yfS)[tid + 256 * k] = fsrc[tid + 256 * k];
        __syncthreads();
        for (int mm = 0; mm < 256; ++mm) {
            const float dx = xx - yS[3 * mm], dy = xy - yS[3 * mm + 1], dz = xz - yS[3 * mm + 2];
            const float d2 = dx * dx + dy * dy + dz * dz;
            const float e2 = __expf(-12.5f * d2);
            const float t = e2 * e2, e1 = t * t, u = e1 * e1, e0 = u * u;
            den0 += e0; den1 += e1; den2 += e2;
            const float4* fr = reinterpret_cast<const float4*>(yfS + mm * 16);
#pragma unroll
            for (int k = 0; k < 4; ++k) {
                const float4 f = fr[k];
                a0[4*k+0] += e0 * f.x; a0[4*k+1] += e0 * f.y; a0[4*k+2] += e0 * f.z; a0[4*k+3] += e0 * f.w;
                a1[4*k+0] += e1 * f.x; a1[4*k+1] += e1 * f.y; a1[4*k+2] += e1 * f.z; a1[4*k+3] += e1 * f.w;
                a2[4*k+0] += e2 * f.x; a2[4*k+1] += e2 * f.y; a2[4*k+2] += e2 * f.z; a2[4*k+3] += e2 * f.w;
            }
        }
        __syncthreads();
    }
    const float r0 = 0.3f / den0, r1 = 0.3f / den1, r2 = 0.4f / den2;
#pragma unroll
    for (int c = 0; c < 16; ++c)
        out[(size_t)n * 16 + c] = a0[c] * r0 + a1[c] * r1 + a2[c] * r2;
}

extern "C" void kernel_launch(void* const* d_in, const int* in_sizes, int n_in,
                              void* d_out, int out_size, void* d_ws, size_t ws_size,
                              hipStream_t stream) {
    const float* x  = (const float*)d_in[0];
    const float* y  = (const float*)d_in[1];
    const float* yf = (const float*)d_in[2];
    float* out = (float*)d_out;

    const size_t fragyB = (size_t)(Mm / 16) * 512 * sizeof(_Float16); // 512 KB
    const size_t fragfB = (size_t)Mm * 16 * sizeof(_Float16);         // 256 KB
    const size_t partB  = (size_t)NCH * Nn * 52 * sizeof(float);      // 13.6 MB
    if (fragyB + fragfB + partB > ws_size) {
        mgsc_fused<<<Nn / 256, 256, 0, stream>>>(x, y, yf, out);
        return;
    }
    _Float16* fragy = (_Float16*)d_ws;
    _Float16* fragf = (_Float16*)((char*)d_ws + fragyB);
    float*    part  = (float*)((char*)d_ws + fragyB + fragfB);

    mgsc_prep<<<(Mm * 32) / 256, 256, 0, stream>>>(y, yf, fragy, fragf);
    mgsc_main<<<dim3(Nn / 64, NCH), 256, 0, stream>>>(x, fragy, fragf, part);
    mgsc_reduce<<<(Nn * 16) / 256, 256, 0, stream>>>(part, out);
}